// Round 7
// baseline (224.749 us; speedup 1.0000x reference)
//
#include <hip/hip_runtime.h>
#include <hip/hip_bf16.h>

#define EE 256
#define SS 2048
#define BB 64
#define RN 50
#define OSTR 8242   // 50 + 4*2048
#define NCH 32      // attend chunks per batch (64 rows each)

typedef __attribute__((ext_vector_type(4))) float vf4;
typedef __attribute__((ext_vector_type(8))) short s8v;
typedef __attribute__((ext_vector_type(4))) short s4v;
typedef __attribute__((ext_vector_type(4))) unsigned short u16x4;
typedef __attribute__((ext_vector_type(2))) unsigned int u32x2;

__device__ __forceinline__ unsigned short f2bf(float f){
  __hip_bfloat16 h = __float2bfloat16(f);          // RNE, hardware cvt
  return *reinterpret_cast<unsigned short*>(&h);
}
__device__ __forceinline__ unsigned int f2bf2(float a, float b){
  __hip_bfloat162 h = __float22bfloat162_rn(make_float2(a, b));  // v_cvt_pk_bf16_f32
  return *reinterpret_cast<unsigned int*>(&h);
}
__device__ __forceinline__ float sigm(float x){ return 1.0f/(1.0f + __expf(-x)); }
__device__ __forceinline__ float dot4(vf4 a, vf4 b){ return a.x*b.x + a.y*b.y + a.z*b.z + a.w*b.w; }

__device__ __forceinline__ vf4 mfma16(s4v a, s4v b, vf4 c){
#if __has_builtin(__builtin_amdgcn_mfma_f32_16x16x16bf16_1k)
  return __builtin_amdgcn_mfma_f32_16x16x16bf16_1k(a, b, c, 0, 0, 0);
#else
  vf4 d;
  asm volatile("v_mfma_f32_16x16x16_bf16 %0, %1, %2, %3\n\ts_nop 7\n\ts_nop 7"
               : "=v"(d) : "v"(a), "v"(b), "v"(c));
  return d;
#endif
}

__device__ __forceinline__ void gload_lds16(const void* g, void* l){
  __builtin_amdgcn_global_load_lds(
      (const __attribute__((address_space(1))) unsigned int*)g,
      (__attribute__((address_space(3))) unsigned int*)l, 16, 0, 0);
}

// ---------------- 1a) fused prep: gather/transpose + WT + Bp -----------------
__global__ __launch_bounds__(256) void k_prep(
  const float* __restrict__ enc, const float* __restrict__ h0, const float* __restrict__ c0,
  const int* __restrict__ r_in, const int* __restrict__ k1, const int* __restrict__ k2,
  const float* __restrict__ sos, const float* __restrict__ rel,
  const float* __restrict__ W_conv,
  float* __restrict__ xT, float* __restrict__ hT0, float* __restrict__ cT,
  unsigned short* __restrict__ WT, unsigned short* __restrict__ Bp)
{
  int bid = blockIdx.x, t = threadIdx.x;
  if (bid < 256){
    int part = bid >> 6, b = bid & 63;
    if (part == 0){
      xT[(size_t)0*EE*BB + t*BB + b] = sos[t];
    } else if (part == 1){
      xT[(size_t)1*EE*BB + t*BB + b] = rel[r_in[b]*EE + t];
    } else if (part == 2){
      int i1 = k1[b], i2 = k2[b];
      xT[(size_t)2*EE*BB + t*BB + b] =
        enc[((size_t)b*SS + i1)*EE + t] + enc[((size_t)b*SS + i2)*EE + t];
    } else {
      hT0[t*BB + b] = h0[b*EE + t];
      cT [t*BB + b] = c0[b*EE + t];
    }
  } else if (bid < 512){
    int o = bid - 256;
    for (int r = t; r < 768; r += 256)
      WT[(size_t)r*EE + o] = f2bf(W_conv[(size_t)o*1536 + 768 + r]);
  } else {
    int gid = (bid - 512)*256 + t;   // < 24576
    int kc  = gid >> 10;
    int rem = gid & 1023;
    int ni  = rem >> 6;
    int l   = rem & 63;
    int o   = ni*16 + (l & 15);
    int kbase = kc*32 + ((l >> 4) << 3);
    u16x4 lo4, hi4;
    #pragma unroll
    for (int j=0;j<8;++j){
      int k = kbase + j; int ktap = k >> 8; int i = k & 255;
      unsigned short v = f2bf(W_conv[((size_t)o*512 + i)*3 + ktap]);
      if (j<4){ if(j==0)lo4.x=v; else if(j==1)lo4.y=v; else if(j==2)lo4.z=v; else lo4.w=v; }
      else    { if(j==4)hi4.x=v; else if(j==5)hi4.y=v; else if(j==6)hi4.z=v; else hi4.w=v; }
    }
    u16x4* dst = (u16x4*)(Bp + (size_t)gid*8);
    dst[0] = lo4; dst[1] = hi4;
  }
}

// ---------------- 1b) one LSTM step: gates GEMV + update ---------------------
__global__ __launch_bounds__(256) void k_step(
  const float* __restrict__ hT_cur, const float* __restrict__ xT_st,
  const float* __restrict__ W_ih, const float* __restrict__ W_hh,
  const float* __restrict__ b_ih, const float* __restrict__ b_hh,
  float* __restrict__ cT, float* __restrict__ hT_next, float* __restrict__ hs_st)
{
  int e = blockIdx.x, tid = threadIdx.x;
  int w = tid >> 6, b = tid & 63;
  int grow = w*EE + e;
  const float* wh = W_hh + (size_t)grow*EE;
  const float* wi = W_ih + (size_t)grow*EE;
  float acc = b_ih[grow] + b_hh[grow];
  #pragma unroll 4
  for (int k4 = 0; k4 < EE/4; ++k4){
    vf4 wh4 = *(const vf4*)(wh + k4*4);
    vf4 wi4 = *(const vf4*)(wi + k4*4);
    int k = k4*4;
    acc += hT_cur[(k+0)*BB+b]*wh4.x + hT_cur[(k+1)*BB+b]*wh4.y
         + hT_cur[(k+2)*BB+b]*wh4.z + hT_cur[(k+3)*BB+b]*wh4.w;
    acc += xT_st[(k+0)*BB+b]*wi4.x + xT_st[(k+1)*BB+b]*wi4.y
         + xT_st[(k+2)*BB+b]*wi4.z + xT_st[(k+3)*BB+b]*wi4.w;
  }
  __shared__ float sm[4][BB];
  sm[w][b] = acc;
  __syncthreads();
  if (tid < BB){
    float iv = sm[0][tid], fv = sm[1][tid], gv = sm[2][tid], ov = sm[3][tid];
    float cprev = cT[e*BB + tid];
    float cn = sigm(fv)*cprev + sigm(iv)*tanhf(gv);
    float hn = sigm(ov)*tanhf(cn);
    cT[e*BB + tid] = cn;
    hT_next[e*BB + tid] = hn;
    hs_st[(size_t)tid*EE + e] = hn;
  }
}

// ---- 2) two-pass attend, no row staging: scores -> softmax -> mix (+encb) ---
// grid: 64 b x 32 chunks of 64 rows; 256 threads (4 waves)
__global__ __launch_bounds__(256) void k_attend(
  const float* __restrict__ enc, const float* __restrict__ hs,
  float* __restrict__ mixc, float* __restrict__ stats,
  unsigned short* __restrict__ encb)
{
  int bid = blockIdx.x; int b = bid >> 5, ch = bid & 31;
  int tid = threadIdx.x, lane = tid & 63, wv = tid >> 6;
  __shared__ float sc[3][64];
  __shared__ vf4 mpart[4][3][64];   // 12 KB

  const float* chunk = enc + ((size_t)b*SS + ch*64)*EE;

  // ---- pass 1: scores. lane = (rs = row-sub 0..3, cg = col-slice 0..15) ----
  {
    int rs = lane >> 4, cg = lane & 15;
    vf4 q0[4], q1[4], q2[4];
    #pragma unroll
    for (int v=0; v<4; ++v){
      q0[v] = *(const vf4*)(hs + ((size_t)0*BB + b)*EE + cg*16 + v*4);
      q1[v] = *(const vf4*)(hs + ((size_t)1*BB + b)*EE + cg*16 + v*4);
      q2[v] = *(const vf4*)(hs + ((size_t)2*BB + b)*EE + cg*16 + v*4);
    }
    #pragma unroll
    for (int i=0; i<4; ++i){
      int r = wv*16 + i*4 + rs;
      const vf4* rp = (const vf4*)(chunk + (size_t)r*EE + cg*16);
      float a0=0.f, a1=0.f, a2=0.f;
      #pragma unroll
      for (int v=0; v<4; ++v){
        vf4 ev = rp[v];
        a0 += dot4(ev, q0[v]); a1 += dot4(ev, q1[v]); a2 += dot4(ev, q2[v]);
      }
      #pragma unroll
      for (int d=1; d<16; d<<=1){
        a0 += __shfl_xor(a0,d); a1 += __shfl_xor(a1,d); a2 += __shfl_xor(a2,d);
      }
      if (cg == 0){ sc[0][r]=a0; sc[1][r]=a1; sc[2][r]=a2; }
    }
  }
  __syncthreads();

  // ---- chunk softmax on wave 0 (row = lane) ----
  if (tid < 64){
    float s0 = sc[0][tid], s1 = sc[1][tid], s2 = sc[2][tid];
    float m0=s0, m1=s1, m2=s2;
    #pragma unroll
    for (int d=1; d<64; d<<=1){
      m0 = fmaxf(m0, __shfl_xor(m0,d));
      m1 = fmaxf(m1, __shfl_xor(m1,d));
      m2 = fmaxf(m2, __shfl_xor(m2,d));
    }
    float e0 = __expf(s0-m0), e1 = __expf(s1-m1), e2 = __expf(s2-m2);
    sc[0][tid]=e0; sc[1][tid]=e1; sc[2][tid]=e2;
    float l0=e0, l1=e1, l2=e2;
    #pragma unroll
    for (int d=1; d<64; d<<=1){
      l0 += __shfl_xor(l0,d); l1 += __shfl_xor(l1,d); l2 += __shfl_xor(l2,d);
    }
    if (tid == 0){
      int o0 = ((0*BB+b)*NCH + ch)*2; stats[o0]=m0; stats[o0+1]=l0;
      int o1 = ((1*BB+b)*NCH + ch)*2; stats[o1]=m1; stats[o1+1]=l1;
      int o2 = ((2*BB+b)*NCH + ch)*2; stats[o2]=m2; stats[o2+1]=l2;
    }
  }
  __syncthreads();

  // ---- pass 2: mix (L2-hot re-read) + contiguous encb write ----
  {
    vf4 A0 = (vf4)0.0f, A1 = (vf4)0.0f, A2 = (vf4)0.0f;
    #pragma unroll 4
    for (int j=0;j<16;++j){
      int r = wv*16 + j;
      int gs = ch*64 + r;
      vf4 ev = *(const vf4*)(chunk + (size_t)r*EE + lane*4);
      if (encb){
        u32x2 pk; pk.x = f2bf2(ev.x, ev.y); pk.y = f2bf2(ev.z, ev.w);
        int key = ((gs + 1) & 7) << 4;
        *(u32x2*)((char*)encb + ((size_t)b*SS + gs)*512 + ((lane*8) ^ key)) = pk;
      }
      float w0 = sc[0][r], w1 = sc[1][r], w2 = sc[2][r];
      A0 += ev*w0; A1 += ev*w1; A2 += ev*w2;
    }
    mpart[wv][0][lane]=A0; mpart[wv][1][lane]=A1; mpart[wv][2][lane]=A2;
  }
  __syncthreads();
  if (tid < 192){
    int q = tid >> 6, e4 = tid & 63;
    vf4 sum = mpart[0][q][e4] + mpart[1][q][e4] + mpart[2][q][e4] + mpart[3][q][e4];
    *(vf4*)(mixc + ((size_t)(q*BB+b)*NCH + ch)*EE + e4*4) = sum;
  }
}

// ------- 4) combine chunk mixes; out_t; t1 logits; V vectors (1024 thr) ------
__global__ __launch_bounds__(1024) void k_post(
  const float* __restrict__ mixc, const float* __restrict__ hs,
  const float* __restrict__ stats,
  const float* __restrict__ W_attn, const float* __restrict__ b_attn,
  const float* __restrict__ W_rel, const float* __restrict__ b_rel,
  const unsigned short* __restrict__ WT, const float* __restrict__ b_conv,
  float* __restrict__ out, float* __restrict__ vv)
{
  int b = blockIdx.x, tid = threadIdx.x;
  __shared__ float comb[3][2*EE];     // 6 KB
  __shared__ float ovs[3][EE];        // 3 KB
  __shared__ float vpart[2][6][EE];   // 12 KB

  // Phase A: combine chunk mixes (768 threads: q x e)
  if (tid < 768){
    int q = tid >> 8, e = tid & 255;
    float M = -1e30f;
    for (int c=0;c<NCH;c++) M = fmaxf(M, stats[((q*BB+b)*NCH + c)*2]);
    float L = 0.f, macc = 0.f;
    for (int c=0;c<NCH;c++){
      int o = ((q*BB+b)*NCH + c)*2;
      float ee = __expf(stats[o]-M);
      L += stats[o+1]*ee;
      macc += mixc[((size_t)(q*BB+b)*NCH + c)*EE + e] * ee;
    }
    comb[q][e] = macc / L;
    comb[q][EE+e] = hs[((size_t)q*BB + b)*EE + e];
  }
  __syncthreads();
  // Phase B: attn GEMV + tanh (768 threads: q x e)
  if (tid < 768){
    int q = tid >> 8, e = tid & 255;
    float a = b_attn[e];
    const vf4* wr = (const vf4*)(W_attn + (size_t)e*2*EE);
    const vf4* cv = (const vf4*)comb[q];
    #pragma unroll 4
    for (int k=0;k<2*EE/4;++k) a += dot4(wr[k], cv[k]);
    ovs[q][e] = tanhf(a);
  }
  __syncthreads();
  // Phase C: V-vector partials (512 threads) || t1 logits (64 threads)
  if (tid < 512){
    int half = tid >> 8, o = tid & 255;
    float va0=0,va1=0,va2=0, vb0=0,vb1=0,vb2=0;
    int i0 = half*128;
    for (int i=i0; i<i0+128; ++i){
      float x2 = ovs[1][i], x3 = ovs[2][i];
      const unsigned short* wt = WT + (size_t)i*3*EE + o;
      float w0 = __uint_as_float(((unsigned int)wt[0]) << 16);
      float w1 = __uint_as_float(((unsigned int)wt[EE]) << 16);
      float w2 = __uint_as_float(((unsigned int)wt[2*EE]) << 16);
      va0 += x2*w0; va1 += x2*w1; va2 += x2*w2;
      vb0 += x3*w0; vb1 += x3*w1; vb2 += x3*w2;
    }
    vpart[half][0][o]=va0; vpart[half][1][o]=va1; vpart[half][2][o]=va2;
    vpart[half][3][o]=vb0; vpart[half][4][o]=vb1; vpart[half][5][o]=vb2;
  } else if (tid < 576){
    int t = tid - 512;
    if (t < RN){
      float acc = b_rel[t];
      const vf4* wrel = (const vf4*)(W_rel + (size_t)t*EE);
      const vf4* ov = (const vf4*)ovs[0];
      for (int k=0;k<EE/4;++k) acc += dot4(wrel[k], ov[k]);
      out[(size_t)b*OSTR + t] = acc;
    }
  }
  __syncthreads();
  // Phase D: combine halves, write vv (256 threads)
  if (tid < 256){
    int o = tid;
    float va0 = vpart[0][0][o]+vpart[1][0][o];
    float va1 = vpart[0][1][o]+vpart[1][1][o];
    float va2 = vpart[0][2][o]+vpart[1][2][o];
    float vb0 = vpart[0][3][o]+vpart[1][3][o];
    float vb1 = vpart[0][4][o]+vpart[1][4][o];
    float vb2 = vpart[0][5][o]+vpart[1][5][o];
    float bc = b_conv[o];
    vv[((0*3+0)*BB + b)*EE + o] = va0+va1+va2+bc;  // interior
    vv[((0*3+1)*BB + b)*EE + o] = va1+va2+bc;      // s==0
    vv[((0*3+2)*BB + b)*EE + o] = va0+va1+bc;      // s==S-1
    vv[((1*3+0)*BB + b)*EE + o] = vb0+vb1+vb2+bc;
    vv[((1*3+1)*BB + b)*EE + o] = vb1+vb2+bc;
    vv[((1*3+2)*BB + b)*EE + o] = vb0+vb1+bc;
  }
}

// ---------------- 6) conv GEMM: C[o][s] = W·enc^T, MFMA relu-dot epilogue ----
__global__ __launch_bounds__(256, 3) void k_conv(
  const float* __restrict__ enc, const unsigned short* __restrict__ encb,
  const unsigned short* __restrict__ Bp,
  const float* __restrict__ vv,
  const float* __restrict__ W_e1, const float* __restrict__ b_e1,
  const float* __restrict__ W_e2, const float* __restrict__ b_e2,
  float* __restrict__ out)
{
  int stile = blockIdx.x, b = blockIdx.y;
  int s0 = stile*64;
  int tid = threadIdx.x, lane = tid & 63, w = tid >> 6;
  int lo = lane & 15, hi = lane >> 4;
  __shared__ __align__(16) unsigned short Ab[66*256];
  __shared__ float part2[4][64][4];

  if (encb){
    const char* ebase = (const char*)encb + (size_t)b*SS*512;
    for (int base = 0; base < 66*32; base += 256){
      int idx = base + tid;
      if (idx < 66*32){
        int r = idx >> 5, c = idx & 31;
        int srow = s0 - 1 + r;
        srow = srow < 0 ? 0 : (srow > SS-1 ? SS-1 : srow);
        gload_lds16(ebase + (size_t)srow*512 + c*16, (char*)Ab + idx*16);
      }
    }
    __syncthreads();
    if (stile == 0 || stile == 31){
      if (stile == 0  && tid < 32) *(vf4*)((char*)Ab + tid*16) = (vf4)0.0f;
      if (stile == 31 && tid < 32) *(vf4*)((char*)Ab + 65*512 + tid*16) = (vf4)0.0f;
      __syncthreads();
    }
  } else {
    const float* eb = enc + (size_t)b*SS*EE;
    for (int idx = tid; idx < 66*64; idx += 256){
      int r = idx >> 6, c4 = idx & 63;
      int s = s0 - 1 + r;
      vf4 v = (vf4)0.0f;
      if (s >= 0 && s < SS) v = *(const vf4*)(eb + (size_t)s*EE + c4*4);
      u32x2 pk; pk.x = f2bf2(v.x, v.y); pk.y = f2bf2(v.z, v.w);
      int byte = (r*512 + c4*8) ^ ((r & 7) << 4);
      *(u32x2*)((char*)Ab + byte) = pk;
    }
    __syncthreads();
  }

  vf4 acc[4][4];   // [oi][si], row=o col=s
  #pragma unroll
  for (int oi=0;oi<4;++oi){
    #pragma unroll
    for (int si=0;si<4;++si) acc[oi][si] = (vf4)0.0f;
  }
  const s8v* Bp8 = (const s8v*)Bp;
  s8v bf[4], bfn[4];
  #pragma unroll
  for (int oi=0;oi<4;++oi) bf[oi] = Bp8[((0*16 + (w*4+oi)) << 6) + lane];

  for (int kc=0; kc<24; ++kc){
    int ktap = kc >> 3;
    int colb = ((kc & 7) << 6) + (hi << 4);
    s8v af[4];
    #pragma unroll
    for (int si=0;si<4;++si){
      int row = si*16 + lo + ktap;
      int byte = row*512 + (colb ^ ((row & 7) << 4));
      af[si] = *(const s8v*)((const char*)Ab + byte);
    }
    if (kc < 23){
      #pragma unroll
      for (int oi=0;oi<4;++oi) bfn[oi] = Bp8[(((kc+1)*16 + (w*4+oi)) << 6) + lane];
    }
    #pragma unroll
    for (int oi=0;oi<4;++oi){
      #pragma unroll
      for (int si=0;si<4;++si)
        acc[oi][si] = __builtin_amdgcn_mfma_f32_16x16x32_bf16(bf[oi], af[si], acc[oi][si], 0, 0, 0);
    }
    #pragma unroll
    for (int oi=0;oi<4;++oi) bf[oi] = bfn[oi];
  }

  bool firstTile = (s0 == 0), lastTile = (s0 + 64 == SS);
  vf4 vaI[4], vbI[4]; s4v aw[4];
  #pragma unroll
  for (int oi=0;oi<4;++oi){
    int o4 = w*64 + oi*16 + hi*4;
    vaI[oi] = *(const vf4*)(vv + ((0*3+0)*BB + b)*EE + o4);
    vbI[oi] = *(const vf4*)(vv + ((1*3+0)*BB + b)*EE + o4);
    vf4 w1 = *(const vf4*)(W_e1 + o4);
    vf4 w2 = *(const vf4*)(W_e2 + o4);
    float e0 = (lo==0) ? w1.x : ((lo==1) ? w2.x : 0.0f);
    float e1 = (lo==0) ? w1.y : ((lo==1) ? w2.y : 0.0f);
    float e2 = (lo==0) ? w1.z : ((lo==1) ? w2.z : 0.0f);
    float e3 = (lo==0) ? w1.w : ((lo==1) ? w2.w : 0.0f);
    u32x2 t; t.x = f2bf2(e0, e1); t.y = f2bf2(e2, e3);
    aw[oi] = __builtin_bit_cast(s4v, t);
  }
  #pragma unroll
  for (int si=0; si<4; ++si){
    vf4 Da = (vf4)0.0f, Db = (vf4)0.0f;
    #pragma unroll
    for (int oi=0; oi<4; ++oi){
      int o4 = w*64 + oi*16 + hi*4;
      vf4 c = acc[oi][si];
      vf4 va = vaI[oi], vb = vbI[oi];
      if (firstTile && si==0 && lo==0){
        va = *(const vf4*)(vv + ((0*3+1)*BB + b)*EE + o4);
        vb = *(const vf4*)(vv + ((1*3+1)*BB + b)*EE + o4);
      }
      if (lastTile && si==3 && lo==15){
        va = *(const vf4*)(vv + ((0*3+2)*BB + b)*EE + o4);
        vb = *(const vf4*)(vv + ((1*3+2)*BB + b)*EE + o4);
      }
      float a0 = fmaxf(c.x+va.x,0.f), a1 = fmaxf(c.y+va.y,0.f);
      float a2 = fmaxf(c.z+va.z,0.f), a3 = fmaxf(c.w+va.w,0.f);
      float b0 = fmaxf(c.x+vb.x,0.f), b1 = fmaxf(c.y+vb.y,0.f);
      float b2 = fmaxf(c.z+vb.z,0.f), b3 = fmaxf(c.w+vb.w,0.f);
      u32x2 ta; ta.x = f2bf2(a0,a1); ta.y = f2bf2(a2,a3);
      u32x2 tb; tb.x = f2bf2(b0,b1); tb.y = f2bf2(b2,b3);
      Da = mfma16(aw[oi], __builtin_bit_cast(s4v, ta), Da);
      Db = mfma16(aw[oi], __builtin_bit_cast(s4v, tb), Db);
    }
    if (hi == 0){
      vf4 pk; pk.x = Da.x; pk.y = Da.y; pk.z = Db.x; pk.w = Db.y;
      *(vf4*)&part2[w][si*16+lo][0] = pk;
    }
  }
  __syncthreads();
  {
    int s = tid >> 2, c = tid & 3;
    float r = part2[0][s][c] + part2[1][s][c] + part2[2][s][c] + part2[3][s][c];
    r += (c & 1) ? b_e2[0] : b_e1[0];
    out[(size_t)b*OSTR + RN + c*SS + (s0 + s)] = r;
  }
}

extern "C" void kernel_launch(void* const* d_in, const int* in_sizes, int n_in,
                              void* d_out, int out_size, void* d_ws, size_t ws_size,
                              hipStream_t stream)
{
  const float* enc   = (const float*)d_in[0];
  const float* h0    = (const float*)d_in[1];
  const float* c0    = (const float*)d_in[2];
  const int*   r_in  = (const int*)d_in[3];
  const int*   k1    = (const int*)d_in[4];
  const int*   k2    = (const int*)d_in[5];
  const float* W_ih  = (const float*)d_in[6];
  const float* W_hh  = (const float*)d_in[7];
  const float* b_ih  = (const float*)d_in[8];
  const float* b_hh  = (const float*)d_in[9];
  const float* W_attn= (const float*)d_in[10];
  const float* b_attn= (const float*)d_in[11];
  const float* W_conv= (const float*)d_in[12];
  const float* b_conv= (const float*)d_in[13];
  const float* sos   = (const float*)d_in[14];
  const float* rel   = (const float*)d_in[15];
  const float* W_rel = (const float*)d_in[16];
  const float* b_rel = (const float*)d_in[17];
  const float* W_e1  = (const float*)d_in[18];
  const float* b_e1  = (const float*)d_in[19];
  const float* W_e2  = (const float*)d_in[20];
  const float* b_e2  = (const float*)d_in[21];
  float* out = (float*)d_out;
  char* ws = (char*)d_ws;

  float* hs    = (float*)(ws);                  // 3*64*256 f32        (196608 B)
  float* vv    = (float*)(ws + 196608);         // 2*3*64*256 f32      (393216 B)
  float* stats = (float*)(ws + 589824);         // 3*64*32*2 f32       ( 49152 B)
  float* mixc  = (float*)(ws + 638976);         // 3*64*32*256 f32     (6291456 B)
  unsigned short* Bp = (unsigned short*)(ws + 6930432);  // (393216 B)
  float* xT    = (float*)(ws + 7323648);        // 3*256*64 f32        (196608 B)
  float* hTa   = (float*)(ws + 7520256);        // 256*64 f32          ( 65536 B)
  float* hTb   = (float*)(ws + 7585792);        // 256*64 f32          ( 65536 B)
  float* cT    = (float*)(ws + 7651328);        // 256*64 f32          ( 65536 B)
  unsigned short* WT = (unsigned short*)(ws + 7716864);  // 768*256 bf16 (393216 B)
  size_t encb_off = 8110080;
  size_t need = encb_off + (size_t)BB*SS*EE*2;           // + 67108864 = ~75.2 MB
  unsigned short* encb = (ws_size >= need) ? (unsigned short*)(ws + encb_off) : nullptr;

  hipLaunchKernelGGL(k_prep,  dim3(608), dim3(256), 0, stream,
                     enc,h0,c0,r_in,k1,k2,sos,rel,W_conv, xT,hTa,cT, WT,Bp);
  hipLaunchKernelGGL(k_step,  dim3(256), dim3(256), 0, stream,
                     hTa, xT + 0*EE*BB, W_ih,W_hh,b_ih,b_hh, cT, hTb, hs + 0*BB*EE);
  hipLaunchKernelGGL(k_step,  dim3(256), dim3(256), 0, stream,
                     hTb, xT + 1*EE*BB, W_ih,W_hh,b_ih,b_hh, cT, hTa, hs + 1*BB*EE);
  hipLaunchKernelGGL(k_step,  dim3(256), dim3(256), 0, stream,
                     hTa, xT + 2*EE*BB, W_ih,W_hh,b_ih,b_hh, cT, hTb, hs + 2*BB*EE);
  hipLaunchKernelGGL(k_attend,dim3(2048), dim3(256), 0, stream, enc, hs, mixc, stats, encb);
  hipLaunchKernelGGL(k_post,  dim3(64),  dim3(1024), 0, stream,
                     mixc, hs, stats, W_attn,b_attn, W_rel,b_rel, WT, b_conv, out, vv);
  hipLaunchKernelGGL(k_conv,  dim3(32,64), dim3(256), 0, stream,
                     enc, encb, Bp, vv, W_e1,b_e1, W_e2,b_e2, out);
}

// Round 8
// 201.166 us; speedup vs baseline: 1.1172x; 1.1172x over previous
//
#include <hip/hip_runtime.h>
#include <hip/hip_bf16.h>

#define EE 256
#define SS 2048
#define BB 64
#define RN 50
#define OSTR 8242   // 50 + 4*2048
#define NCH 32      // attend chunks per batch (64 rows each)

typedef __attribute__((ext_vector_type(4))) float vf4;
typedef __attribute__((ext_vector_type(8))) short s8v;
typedef __attribute__((ext_vector_type(4))) short s4v;
typedef __attribute__((ext_vector_type(4))) unsigned short u16x4;
typedef __attribute__((ext_vector_type(2))) unsigned int u32x2;
typedef __attribute__((ext_vector_type(4))) unsigned int u32x4;

__device__ __forceinline__ unsigned short f2bf(float f){
  __hip_bfloat16 h = __float2bfloat16(f);          // RNE, hardware cvt
  return *reinterpret_cast<unsigned short*>(&h);
}
__device__ __forceinline__ unsigned int f2bf2(float a, float b){
  __hip_bfloat162 h = __float22bfloat162_rn(make_float2(a, b));  // v_cvt_pk_bf16_f32
  return *reinterpret_cast<unsigned int*>(&h);
}
__device__ __forceinline__ float sigm(float x){ return 1.0f/(1.0f + __expf(-x)); }
__device__ __forceinline__ float dot4(vf4 a, vf4 b){ return a.x*b.x + a.y*b.y + a.z*b.z + a.w*b.w; }

__device__ __forceinline__ vf4 mfma16(s4v a, s4v b, vf4 c){
#if __has_builtin(__builtin_amdgcn_mfma_f32_16x16x16bf16_1k)
  return __builtin_amdgcn_mfma_f32_16x16x16bf16_1k(a, b, c, 0, 0, 0);
#else
  vf4 d;
  asm volatile("v_mfma_f32_16x16x16_bf16 %0, %1, %2, %3\n\ts_nop 7\n\ts_nop 7"
               : "=v"(d) : "v"(a), "v"(b), "v"(c));
  return d;
#endif
}

__device__ __forceinline__ void gload_lds16(const void* g, void* l){
  __builtin_amdgcn_global_load_lds(
      (const __attribute__((address_space(1))) unsigned int*)g,
      (__attribute__((address_space(3))) unsigned int*)l, 16, 0, 0);
}

// ---------------- 1a) fused prep: gather/transpose + WT + Bp -----------------
__global__ __launch_bounds__(256) void k_prep(
  const float* __restrict__ enc, const float* __restrict__ h0, const float* __restrict__ c0,
  const int* __restrict__ r_in, const int* __restrict__ k1, const int* __restrict__ k2,
  const float* __restrict__ sos, const float* __restrict__ rel,
  const float* __restrict__ W_conv,
  float* __restrict__ xT, float* __restrict__ hT0, float* __restrict__ cT,
  unsigned short* __restrict__ WT, unsigned short* __restrict__ Bp)
{
  int bid = blockIdx.x, t = threadIdx.x;
  if (bid < 256){
    int part = bid >> 6, b = bid & 63;
    if (part == 0){
      xT[(size_t)0*EE*BB + t*BB + b] = sos[t];
    } else if (part == 1){
      xT[(size_t)1*EE*BB + t*BB + b] = rel[r_in[b]*EE + t];
    } else if (part == 2){
      int i1 = k1[b], i2 = k2[b];
      xT[(size_t)2*EE*BB + t*BB + b] =
        enc[((size_t)b*SS + i1)*EE + t] + enc[((size_t)b*SS + i2)*EE + t];
    } else {
      hT0[t*BB + b] = h0[b*EE + t];
      cT [t*BB + b] = c0[b*EE + t];
    }
  } else if (bid < 512){
    int o = bid - 256;
    for (int r = t; r < 768; r += 256)
      WT[(size_t)r*EE + o] = f2bf(W_conv[(size_t)o*1536 + 768 + r]);
  } else {
    int gid = (bid - 512)*256 + t;   // < 24576
    int kc  = gid >> 10;
    int rem = gid & 1023;
    int ni  = rem >> 6;
    int l   = rem & 63;
    int o   = ni*16 + (l & 15);
    int kbase = kc*32 + ((l >> 4) << 3);
    u16x4 lo4, hi4;
    #pragma unroll
    for (int j=0;j<8;++j){
      int k = kbase + j; int ktap = k >> 8; int i = k & 255;
      unsigned short v = f2bf(W_conv[((size_t)o*512 + i)*3 + ktap]);
      if (j<4){ if(j==0)lo4.x=v; else if(j==1)lo4.y=v; else if(j==2)lo4.z=v; else lo4.w=v; }
      else    { if(j==4)hi4.x=v; else if(j==5)hi4.y=v; else if(j==6)hi4.z=v; else hi4.w=v; }
    }
    u16x4* dst = (u16x4*)(Bp + (size_t)gid*8);
    dst[0] = lo4; dst[1] = hi4;
  }
}

// ---------------- 1b) one LSTM step: gates GEMV + update ---------------------
__global__ __launch_bounds__(256) void k_step(
  const float* __restrict__ hT_cur, const float* __restrict__ xT_st,
  const float* __restrict__ W_ih, const float* __restrict__ W_hh,
  const float* __restrict__ b_ih, const float* __restrict__ b_hh,
  float* __restrict__ cT, float* __restrict__ hT_next, float* __restrict__ hs_st)
{
  int e = blockIdx.x, tid = threadIdx.x;
  int w = tid >> 6, b = tid & 63;
  int grow = w*EE + e;
  const float* wh = W_hh + (size_t)grow*EE;
  const float* wi = W_ih + (size_t)grow*EE;
  float acc = b_ih[grow] + b_hh[grow];
  #pragma unroll 4
  for (int k4 = 0; k4 < EE/4; ++k4){
    vf4 wh4 = *(const vf4*)(wh + k4*4);
    vf4 wi4 = *(const vf4*)(wi + k4*4);
    int k = k4*4;
    acc += hT_cur[(k+0)*BB+b]*wh4.x + hT_cur[(k+1)*BB+b]*wh4.y
         + hT_cur[(k+2)*BB+b]*wh4.z + hT_cur[(k+3)*BB+b]*wh4.w;
    acc += xT_st[(k+0)*BB+b]*wi4.x + xT_st[(k+1)*BB+b]*wi4.y
         + xT_st[(k+2)*BB+b]*wi4.z + xT_st[(k+3)*BB+b]*wi4.w;
  }
  __shared__ float sm[4][BB];
  sm[w][b] = acc;
  __syncthreads();
  if (tid < BB){
    float iv = sm[0][tid], fv = sm[1][tid], gv = sm[2][tid], ov = sm[3][tid];
    float cprev = cT[e*BB + tid];
    float cn = sigm(fv)*cprev + sigm(iv)*tanhf(gv);
    float hn = sigm(ov)*tanhf(cn);
    cT[e*BB + tid] = cn;
    hT_next[e*BB + tid] = hn;
    hs_st[(size_t)tid*EE + e] = hn;
  }
}

// ---- 2) single-pass register-held attend: scores+softmax+mix (+encb) --------
// grid: 64 b x 32 chunks of 64 rows; 256 threads (4 waves)
// thread (wv, rs=lane>>4, cg=lane&15) holds rows {wv*16+i*4+rs}, cols [cg*16,+16)
__global__ __launch_bounds__(256) void k_attend(
  const float* __restrict__ enc, const float* __restrict__ hs,
  float* __restrict__ mixc, float* __restrict__ stats,
  unsigned short* __restrict__ encb)
{
  int bid = blockIdx.x; int b = bid >> 5, ch = bid & 31;
  int tid = threadIdx.x, lane = tid & 63, wv = tid >> 6;
  int rs = lane >> 4, cg = lane & 15;
  __shared__ float qsm[3][EE];      // 3 KB
  __shared__ float sc[3][64];
  __shared__ vf4 mpart[4][3][64];   // 12 KB

  const float* chunk = enc + ((size_t)b*SS + ch*64)*EE;

  // issue ALL enc loads upfront (only read of enc in this kernel)
  vf4 dat[4][4];
  #pragma unroll
  for (int i=0;i<4;++i){
    const vf4* rp = (const vf4*)(chunk + (size_t)(wv*16 + i*4 + rs)*EE + cg*16);
    #pragma unroll
    for (int v=0;v<4;++v) dat[i][v] = rp[v];
  }
  for (int i = tid; i < 3*EE; i += 256)
    qsm[i>>8][i&255] = hs[((size_t)(i>>8)*BB + b)*EE + (i&255)];
  __syncthreads();

  // scores from registers
  {
    vf4 q0[4], q1[4], q2[4];
    #pragma unroll
    for (int v=0;v<4;++v){
      q0[v] = *(const vf4*)(qsm[0] + cg*16 + v*4);
      q1[v] = *(const vf4*)(qsm[1] + cg*16 + v*4);
      q2[v] = *(const vf4*)(qsm[2] + cg*16 + v*4);
    }
    #pragma unroll
    for (int i=0;i<4;++i){
      float a0=0.f, a1=0.f, a2=0.f;
      #pragma unroll
      for (int v=0;v<4;++v){
        a0 += dot4(dat[i][v], q0[v]);
        a1 += dot4(dat[i][v], q1[v]);
        a2 += dot4(dat[i][v], q2[v]);
      }
      #pragma unroll
      for (int d=1; d<16; d<<=1){
        a0 += __shfl_xor(a0,d); a1 += __shfl_xor(a1,d); a2 += __shfl_xor(a2,d);
      }
      if (cg == 0){
        int r = wv*16 + i*4 + rs;
        sc[0][r]=a0; sc[1][r]=a1; sc[2][r]=a2;
      }
    }
  }
  __syncthreads();

  // softmax: every wave redundantly, lane owns row=lane
  float e0, e1, e2;
  {
    float s0 = sc[0][lane], s1 = sc[1][lane], s2 = sc[2][lane];
    float m0=s0, m1=s1, m2=s2;
    #pragma unroll
    for (int d=1; d<64; d<<=1){
      m0 = fmaxf(m0, __shfl_xor(m0,d));
      m1 = fmaxf(m1, __shfl_xor(m1,d));
      m2 = fmaxf(m2, __shfl_xor(m2,d));
    }
    e0 = __expf(s0-m0); e1 = __expf(s1-m1); e2 = __expf(s2-m2);
    float l0=e0, l1=e1, l2=e2;
    #pragma unroll
    for (int d=1; d<64; d<<=1){
      l0 += __shfl_xor(l0,d); l1 += __shfl_xor(l1,d); l2 += __shfl_xor(l2,d);
    }
    if (tid == 0){
      int o0 = ((0*BB+b)*NCH + ch)*2; stats[o0]=m0; stats[o0+1]=l0;
      int o1 = ((1*BB+b)*NCH + ch)*2; stats[o1]=m1; stats[o1+1]=l1;
      int o2 = ((2*BB+b)*NCH + ch)*2; stats[o2]=m2; stats[o2+1]=l2;
    }
  }

  // mix + encb write, all from held registers (no enc re-read)
  vf4 A0[4], A1[4], A2[4];
  #pragma unroll
  for (int v=0;v<4;++v){ A0[v]=(vf4)0.0f; A1[v]=(vf4)0.0f; A2[v]=(vf4)0.0f; }
  #pragma unroll
  for (int i=0;i<4;++i){
    int r = wv*16 + i*4 + rs;
    int gs = ch*64 + r;
    float w0 = __shfl(e0, r), w1 = __shfl(e1, r), w2 = __shfl(e2, r);
    if (encb){
      int key = ((gs + 1) & 7) << 4;
      char* base = (char*)encb + ((size_t)b*SS + gs)*512;
      u32x4 lo4, hi4;
      lo4.x = f2bf2(dat[i][0].x, dat[i][0].y); lo4.y = f2bf2(dat[i][0].z, dat[i][0].w);
      lo4.z = f2bf2(dat[i][1].x, dat[i][1].y); lo4.w = f2bf2(dat[i][1].z, dat[i][1].w);
      hi4.x = f2bf2(dat[i][2].x, dat[i][2].y); hi4.y = f2bf2(dat[i][2].z, dat[i][2].w);
      hi4.z = f2bf2(dat[i][3].x, dat[i][3].y); hi4.w = f2bf2(dat[i][3].z, dat[i][3].w);
      *(u32x4*)(base + ((cg*32     ) ^ key)) = lo4;
      *(u32x4*)(base + ((cg*32 + 16) ^ key)) = hi4;
    }
    #pragma unroll
    for (int v=0;v<4;++v){
      A0[v] += dat[i][v]*w0; A1[v] += dat[i][v]*w1; A2[v] += dat[i][v]*w2;
    }
  }
  // reduce partials across rs (lanes ^16, ^32)
  #pragma unroll
  for (int v=0;v<4;++v){
    #pragma unroll
    for (int d=16; d<64; d<<=1){
      A0[v].x += __shfl_xor(A0[v].x,d); A0[v].y += __shfl_xor(A0[v].y,d);
      A0[v].z += __shfl_xor(A0[v].z,d); A0[v].w += __shfl_xor(A0[v].w,d);
      A1[v].x += __shfl_xor(A1[v].x,d); A1[v].y += __shfl_xor(A1[v].y,d);
      A1[v].z += __shfl_xor(A1[v].z,d); A1[v].w += __shfl_xor(A1[v].w,d);
      A2[v].x += __shfl_xor(A2[v].x,d); A2[v].y += __shfl_xor(A2[v].y,d);
      A2[v].z += __shfl_xor(A2[v].z,d); A2[v].w += __shfl_xor(A2[v].w,d);
    }
  }
  if (rs == 0){
    #pragma unroll
    for (int v=0;v<4;++v){
      mpart[wv][0][cg*4+v] = A0[v];
      mpart[wv][1][cg*4+v] = A1[v];
      mpart[wv][2][cg*4+v] = A2[v];
    }
  }
  __syncthreads();
  if (tid < 192){
    int q = tid >> 6, e4 = tid & 63;
    vf4 sum = mpart[0][q][e4] + mpart[1][q][e4] + mpart[2][q][e4] + mpart[3][q][e4];
    *(vf4*)(mixc + ((size_t)(q*BB+b)*NCH + ch)*EE + e4*4) = sum;
  }
}

// ---------------- 4) combine chunk mixes; out_t; t1 logits; V vectors --------
__global__ __launch_bounds__(256) void k_post(
  const float* __restrict__ mixc, const float* __restrict__ hs,
  const float* __restrict__ stats,
  const float* __restrict__ W_attn, const float* __restrict__ b_attn,
  const float* __restrict__ W_rel, const float* __restrict__ b_rel,
  const unsigned short* __restrict__ WT, const float* __restrict__ b_conv,
  float* __restrict__ out, float* __restrict__ vv)
{
  int b = blockIdx.x, t = threadIdx.x;
  __shared__ float comb[3][2*EE];
  __shared__ float o1[EE], o2s[EE], o3s[EE];
  #pragma unroll
  for (int q=0;q<3;q++){
    float M = -1e30f;
    for (int c=0;c<NCH;c++) M = fmaxf(M, stats[((q*BB+b)*NCH + c)*2]);
    float L = 0.f, macc = 0.f;
    for (int c=0;c<NCH;c++){
      int o = ((q*BB+b)*NCH + c)*2;
      float e = __expf(stats[o]-M);
      L += stats[o+1]*e;
      macc += mixc[((size_t)(q*BB+b)*NCH + c)*EE + t] * e;
    }
    comb[q][t] = macc / L;
    comb[q][EE+t] = hs[((size_t)q*BB + b)*EE + t];
  }
  __syncthreads();
  float a0 = b_attn[t], a1 = a0, a2 = a0;
  const vf4* wr = (const vf4*)(W_attn + (size_t)t*2*EE);
  const vf4* c0v = (const vf4*)comb[0];
  const vf4* c1v = (const vf4*)comb[1];
  const vf4* c2v = (const vf4*)comb[2];
  #pragma unroll 4
  for (int k=0;k<2*EE/4;++k){
    vf4 w = wr[k];
    a0 += dot4(w, c0v[k]); a1 += dot4(w, c1v[k]); a2 += dot4(w, c2v[k]);
  }
  o1[t]=tanhf(a0); o2s[t]=tanhf(a1); o3s[t]=tanhf(a2);
  __syncthreads();
  if (t < RN){
    float acc = b_rel[t];
    const vf4* wrel = (const vf4*)(W_rel + (size_t)t*EE);
    const vf4* ov = (const vf4*)o1;
    for (int k=0;k<EE/4;++k) acc += dot4(wrel[k], ov[k]);
    out[(size_t)b*OSTR + t] = acc;
  }
  // V_k[o] = sum_i o[i]*WT[(i*3+k)][o]  (coalesced bf16 rows)
  float va0=0,va1=0,va2=0, vb0=0,vb1=0,vb2=0;
  for (int i=0;i<EE;++i){
    float x2 = o2s[i], x3 = o3s[i];
    const unsigned short* wt = WT + (size_t)i*3*EE + t;
    float w0 = __uint_as_float(((unsigned int)wt[0]) << 16);
    float w1 = __uint_as_float(((unsigned int)wt[EE]) << 16);
    float w2 = __uint_as_float(((unsigned int)wt[2*EE]) << 16);
    va0 += x2*w0; va1 += x2*w1; va2 += x2*w2;
    vb0 += x3*w0; vb1 += x3*w1; vb2 += x3*w2;
  }
  float bc = b_conv[t];
  vv[((0*3+0)*BB + b)*EE + t] = va0+va1+va2+bc;  // interior
  vv[((0*3+1)*BB + b)*EE + t] = va1+va2+bc;      // s==0 (tap0 clipped)
  vv[((0*3+2)*BB + b)*EE + t] = va0+va1+bc;      // s==S-1 (tap2 clipped)
  vv[((1*3+0)*BB + b)*EE + t] = vb0+vb1+vb2+bc;
  vv[((1*3+1)*BB + b)*EE + t] = vb1+vb2+bc;
  vv[((1*3+2)*BB + b)*EE + t] = vb0+vb1+bc;
}

// ---------------- 6) conv GEMM: C[o][s] = W·enc^T, MFMA relu-dot epilogue ----
__global__ __launch_bounds__(256, 3) void k_conv(
  const float* __restrict__ enc, const unsigned short* __restrict__ encb,
  const unsigned short* __restrict__ Bp,
  const float* __restrict__ vv,
  const float* __restrict__ W_e1, const float* __restrict__ b_e1,
  const float* __restrict__ W_e2, const float* __restrict__ b_e2,
  float* __restrict__ out)
{
  int stile = blockIdx.x, b = blockIdx.y;
  int s0 = stile*64;
  int tid = threadIdx.x, lane = tid & 63, w = tid >> 6;
  int lo = lane & 15, hi = lane >> 4;
  __shared__ __align__(16) unsigned short Ab[66*256];
  __shared__ float part2[4][64][4];

  if (encb){
    const char* ebase = (const char*)encb + (size_t)b*SS*512;
    for (int base = 0; base < 66*32; base += 256){
      int idx = base + tid;
      if (idx < 66*32){
        int r = idx >> 5, c = idx & 31;
        int srow = s0 - 1 + r;
        srow = srow < 0 ? 0 : (srow > SS-1 ? SS-1 : srow);
        gload_lds16(ebase + (size_t)srow*512 + c*16, (char*)Ab + idx*16);
      }
    }
    __syncthreads();
    if (stile == 0 || stile == 31){
      if (stile == 0  && tid < 32) *(vf4*)((char*)Ab + tid*16) = (vf4)0.0f;
      if (stile == 31 && tid < 32) *(vf4*)((char*)Ab + 65*512 + tid*16) = (vf4)0.0f;
      __syncthreads();
    }
  } else {
    const float* eb = enc + (size_t)b*SS*EE;
    for (int idx = tid; idx < 66*64; idx += 256){
      int r = idx >> 6, c4 = idx & 63;
      int s = s0 - 1 + r;
      vf4 v = (vf4)0.0f;
      if (s >= 0 && s < SS) v = *(const vf4*)(eb + (size_t)s*EE + c4*4);
      u32x2 pk; pk.x = f2bf2(v.x, v.y); pk.y = f2bf2(v.z, v.w);
      int byte = (r*512 + c4*8) ^ ((r & 7) << 4);
      *(u32x2*)((char*)Ab + byte) = pk;
    }
    __syncthreads();
  }

  vf4 acc[4][4];   // [oi][si], row=o col=s
  #pragma unroll
  for (int oi=0;oi<4;++oi){
    #pragma unroll
    for (int si=0;si<4;++si) acc[oi][si] = (vf4)0.0f;
  }
  const s8v* Bp8 = (const s8v*)Bp;
  s8v bf[4], bfn[4];
  #pragma unroll
  for (int oi=0;oi<4;++oi) bf[oi] = Bp8[((0*16 + (w*4+oi)) << 6) + lane];

  for (int kc=0; kc<24; ++kc){
    int ktap = kc >> 3;
    int colb = ((kc & 7) << 6) + (hi << 4);
    s8v af[4];
    #pragma unroll
    for (int si=0;si<4;++si){
      int row = si*16 + lo + ktap;
      int byte = row*512 + (colb ^ ((row & 7) << 4));
      af[si] = *(const s8v*)((const char*)Ab + byte);
    }
    if (kc < 23){
      #pragma unroll
      for (int oi=0;oi<4;++oi) bfn[oi] = Bp8[(((kc+1)*16 + (w*4+oi)) << 6) + lane];
    }
    #pragma unroll
    for (int oi=0;oi<4;++oi){
      #pragma unroll
      for (int si=0;si<4;++si)
        acc[oi][si] = __builtin_amdgcn_mfma_f32_16x16x32_bf16(bf[oi], af[si], acc[oi][si], 0, 0, 0);
    }
    #pragma unroll
    for (int oi=0;oi<4;++oi) bf[oi] = bfn[oi];
  }

  bool firstTile = (s0 == 0), lastTile = (s0 + 64 == SS);
  vf4 vaI[4], vbI[4]; s4v aw[4];
  #pragma unroll
  for (int oi=0;oi<4;++oi){
    int o4 = w*64 + oi*16 + hi*4;
    vaI[oi] = *(const vf4*)(vv + ((0*3+0)*BB + b)*EE + o4);
    vbI[oi] = *(const vf4*)(vv + ((1*3+0)*BB + b)*EE + o4);
    vf4 w1 = *(const vf4*)(W_e1 + o4);
    vf4 w2 = *(const vf4*)(W_e2 + o4);
    float e0 = (lo==0) ? w1.x : ((lo==1) ? w2.x : 0.0f);
    float e1 = (lo==0) ? w1.y : ((lo==1) ? w2.y : 0.0f);
    float e2 = (lo==0) ? w1.z : ((lo==1) ? w2.z : 0.0f);
    float e3 = (lo==0) ? w1.w : ((lo==1) ? w2.w : 0.0f);
    u32x2 t; t.x = f2bf2(e0, e1); t.y = f2bf2(e2, e3);
    aw[oi] = __builtin_bit_cast(s4v, t);
  }
  #pragma unroll
  for (int si=0; si<4; ++si){
    vf4 Da = (vf4)0.0f, Db = (vf4)0.0f;
    #pragma unroll
    for (int oi=0; oi<4; ++oi){
      int o4 = w*64 + oi*16 + hi*4;
      vf4 c = acc[oi][si];
      vf4 va = vaI[oi], vb = vbI[oi];
      if (firstTile && si==0 && lo==0){
        va = *(const vf4*)(vv + ((0*3+1)*BB + b)*EE + o4);
        vb = *(const vf4*)(vv + ((1*3+1)*BB + b)*EE + o4);
      }
      if (lastTile && si==3 && lo==15){
        va = *(const vf4*)(vv + ((0*3+2)*BB + b)*EE + o4);
        vb = *(const vf4*)(vv + ((1*3+2)*BB + b)*EE + o4);
      }
      float a0 = fmaxf(c.x+va.x,0.f), a1 = fmaxf(c.y+va.y,0.f);
      float a2 = fmaxf(c.z+va.z,0.f), a3 = fmaxf(c.w+va.w,0.f);
      float b0 = fmaxf(c.x+vb.x,0.f), b1 = fmaxf(c.y+vb.y,0.f);
      float b2 = fmaxf(c.z+vb.z,0.f), b3 = fmaxf(c.w+vb.w,0.f);
      u32x2 ta; ta.x = f2bf2(a0,a1); ta.y = f2bf2(a2,a3);
      u32x2 tb; tb.x = f2bf2(b0,b1); tb.y = f2bf2(b2,b3);
      Da = mfma16(aw[oi], __builtin_bit_cast(s4v, ta), Da);
      Db = mfma16(aw[oi], __builtin_bit_cast(s4v, tb), Db);
    }
    if (hi == 0){
      vf4 pk; pk.x = Da.x; pk.y = Da.y; pk.z = Db.x; pk.w = Db.y;
      *(vf4*)&part2[w][si*16+lo][0] = pk;
    }
  }
  __syncthreads();
  {
    int s = tid >> 2, c = tid & 3;
    float r = part2[0][s][c] + part2[1][s][c] + part2[2][s][c] + part2[3][s][c];
    r += (c & 1) ? b_e2[0] : b_e1[0];
    out[(size_t)b*OSTR + RN + c*SS + (s0 + s)] = r;
  }
}

extern "C" void kernel_launch(void* const* d_in, const int* in_sizes, int n_in,
                              void* d_out, int out_size, void* d_ws, size_t ws_size,
                              hipStream_t stream)
{
  const float* enc   = (const float*)d_in[0];
  const float* h0    = (const float*)d_in[1];
  const float* c0    = (const float*)d_in[2];
  const int*   r_in  = (const int*)d_in[3];
  const int*   k1    = (const int*)d_in[4];
  const int*   k2    = (const int*)d_in[5];
  const float* W_ih  = (const float*)d_in[6];
  const float* W_hh  = (const float*)d_in[7];
  const float* b_ih  = (const float*)d_in[8];
  const float* b_hh  = (const float*)d_in[9];
  const float* W_attn= (const float*)d_in[10];
  const float* b_attn= (const float*)d_in[11];
  const float* W_conv= (const float*)d_in[12];
  const float* b_conv= (const float*)d_in[13];
  const float* sos   = (const float*)d_in[14];
  const float* rel   = (const float*)d_in[15];
  const float* W_rel = (const float*)d_in[16];
  const float* b_rel = (const float*)d_in[17];
  const float* W_e1  = (const float*)d_in[18];
  const float* b_e1  = (const float*)d_in[19];
  const float* W_e2  = (const float*)d_in[20];
  const float* b_e2  = (const float*)d_in[21];
  float* out = (float*)d_out;
  char* ws = (char*)d_ws;

  float* hs    = (float*)(ws);                  // 3*64*256 f32        (196608 B)
  float* vv    = (float*)(ws + 196608);         // 2*3*64*256 f32      (393216 B)
  float* stats = (float*)(ws + 589824);         // 3*64*32*2 f32       ( 49152 B)
  float* mixc  = (float*)(ws + 638976);         // 3*64*32*256 f32     (6291456 B)
  unsigned short* Bp = (unsigned short*)(ws + 6930432);  // (393216 B)
  float* xT    = (float*)(ws + 7323648);        // 3*256*64 f32        (196608 B)
  float* hTa   = (float*)(ws + 7520256);        // 256*64 f32          ( 65536 B)
  float* hTb   = (float*)(ws + 7585792);        // 256*64 f32          ( 65536 B)
  float* cT    = (float*)(ws + 7651328);        // 256*64 f32          ( 65536 B)
  unsigned short* WT = (unsigned short*)(ws + 7716864);  // 768*256 bf16 (393216 B)
  size_t encb_off = 8110080;
  size_t need = encb_off + (size_t)BB*SS*EE*2;           // + 67108864 = ~75.2 MB
  unsigned short* encb = (ws_size >= need) ? (unsigned short*)(ws + encb_off) : nullptr;

  hipLaunchKernelGGL(k_prep,  dim3(608), dim3(256), 0, stream,
                     enc,h0,c0,r_in,k1,k2,sos,rel,W_conv, xT,hTa,cT, WT,Bp);
  hipLaunchKernelGGL(k_step,  dim3(256), dim3(256), 0, stream,
                     hTa, xT + 0*EE*BB, W_ih,W_hh,b_ih,b_hh, cT, hTb, hs + 0*BB*EE);
  hipLaunchKernelGGL(k_step,  dim3(256), dim3(256), 0, stream,
                     hTb, xT + 1*EE*BB, W_ih,W_hh,b_ih,b_hh, cT, hTa, hs + 1*BB*EE);
  hipLaunchKernelGGL(k_step,  dim3(256), dim3(256), 0, stream,
                     hTa, xT + 2*EE*BB, W_ih,W_hh,b_ih,b_hh, cT, hTb, hs + 2*BB*EE);
  hipLaunchKernelGGL(k_attend,dim3(2048), dim3(256), 0, stream, enc, hs, mixc, stats, encb);
  hipLaunchKernelGGL(k_post,  dim3(64),  dim3(256), 0, stream,
                     mixc, hs, stats, W_attn,b_attn, W_rel,b_rel, WT, b_conv, out, vv);
  hipLaunchKernelGGL(k_conv,  dim3(32,64), dim3(256), 0, stream,
                     enc, encb, Bp, vv, W_e1,b_e1, W_e2,b_e2, out);
}

// Round 10
// 182.239 us; speedup vs baseline: 1.2333x; 1.1039x over previous
//
#include <hip/hip_runtime.h>
#include <hip/hip_bf16.h>

#define EE 256
#define SS 2048
#define BB 64
#define RN 50
#define OSTR 8242   // 50 + 4*2048
#define NCH 32      // attend chunks per batch (64 rows each)

typedef __attribute__((ext_vector_type(4))) float vf4;
typedef __attribute__((ext_vector_type(8))) short s8v;
typedef __attribute__((ext_vector_type(4))) short s4v;
typedef __attribute__((ext_vector_type(4))) unsigned short u16x4;
typedef __attribute__((ext_vector_type(2))) unsigned int u32x2;
typedef __attribute__((ext_vector_type(4))) unsigned int u32x4;

__device__ __forceinline__ unsigned short f2bf(float f){
  __hip_bfloat16 h = __float2bfloat16(f);          // RNE, hardware cvt
  return *reinterpret_cast<unsigned short*>(&h);
}
__device__ __forceinline__ unsigned int f2bf2(float a, float b){
  __hip_bfloat162 h = __float22bfloat162_rn(make_float2(a, b));  // v_cvt_pk_bf16_f32
  return *reinterpret_cast<unsigned int*>(&h);
}
__device__ __forceinline__ float sigm(float x){ return 1.0f/(1.0f + __expf(-x)); }
__device__ __forceinline__ float dot4(vf4 a, vf4 b){ return a.x*b.x + a.y*b.y + a.z*b.z + a.w*b.w; }

__device__ __forceinline__ vf4 mfma16(s4v a, s4v b, vf4 c){
#if __has_builtin(__builtin_amdgcn_mfma_f32_16x16x16bf16_1k)
  return __builtin_amdgcn_mfma_f32_16x16x16bf16_1k(a, b, c, 0, 0, 0);
#else
  vf4 d;
  asm volatile("v_mfma_f32_16x16x16_bf16 %0, %1, %2, %3\n\ts_nop 7\n\ts_nop 7"
               : "=v"(d) : "v"(a), "v"(b), "v"(c));
  return d;
#endif
}

__device__ __forceinline__ void gload_lds16(const void* g, void* l){
  __builtin_amdgcn_global_load_lds(
      (const __attribute__((address_space(1))) unsigned int*)g,
      (__attribute__((address_space(3))) unsigned int*)l, 16, 0, 0);
}

// ---------------- 1a) fused prep: gather/transpose + WT + Bp -----------------
__global__ __launch_bounds__(256) void k_prep(
  const float* __restrict__ enc, const float* __restrict__ h0, const float* __restrict__ c0,
  const int* __restrict__ r_in, const int* __restrict__ k1, const int* __restrict__ k2,
  const float* __restrict__ sos, const float* __restrict__ rel,
  const float* __restrict__ W_conv,
  float* __restrict__ xT, float* __restrict__ hT0, float* __restrict__ cT,
  unsigned short* __restrict__ WT, unsigned short* __restrict__ Bp)
{
  int bid = blockIdx.x, t = threadIdx.x;
  if (bid < 256){
    int part = bid >> 6, b = bid & 63;
    if (part == 0){
      xT[(size_t)0*EE*BB + t*BB + b] = sos[t];
    } else if (part == 1){
      xT[(size_t)1*EE*BB + t*BB + b] = rel[r_in[b]*EE + t];
    } else if (part == 2){
      int i1 = k1[b], i2 = k2[b];
      xT[(size_t)2*EE*BB + t*BB + b] =
        enc[((size_t)b*SS + i1)*EE + t] + enc[((size_t)b*SS + i2)*EE + t];
    } else {
      hT0[t*BB + b] = h0[b*EE + t];
      cT [t*BB + b] = c0[b*EE + t];
    }
  } else if (bid < 512){
    int o = bid - 256;
    for (int r = t; r < 768; r += 256)
      WT[(size_t)r*EE + o] = f2bf(W_conv[(size_t)o*1536 + 768 + r]);
  } else {
    int gid = (bid - 512)*256 + t;   // < 24576
    int kc  = gid >> 10;
    int rem = gid & 1023;
    int ni  = rem >> 6;
    int l   = rem & 63;
    int o   = ni*16 + (l & 15);
    int kbase = kc*32 + ((l >> 4) << 3);
    u16x4 lo4, hi4;
    #pragma unroll
    for (int j=0;j<8;++j){
      int k = kbase + j; int ktap = k >> 8; int i = k & 255;
      unsigned short v = f2bf(W_conv[((size_t)o*512 + i)*3 + ktap]);
      if (j<4){ if(j==0)lo4.x=v; else if(j==1)lo4.y=v; else if(j==2)lo4.z=v; else lo4.w=v; }
      else    { if(j==4)hi4.x=v; else if(j==5)hi4.y=v; else if(j==6)hi4.z=v; else hi4.w=v; }
    }
    u16x4* dst = (u16x4*)(Bp + (size_t)gid*8);
    dst[0] = lo4; dst[1] = hi4;
  }
}

// ------- 1b) one LSTM step: 1024 thr = (gate, K-quarter); GEMV + update ------
__global__ __launch_bounds__(1024) void k_step(
  const float* __restrict__ hT_cur, const float* __restrict__ xT_st,
  const float* __restrict__ W_ih, const float* __restrict__ W_hh,
  const float* __restrict__ b_ih, const float* __restrict__ b_hh,
  float* __restrict__ cT, float* __restrict__ hT_next, float* __restrict__ hs_st)
{
  int e = blockIdx.x, tid = threadIdx.x;
  int w = tid >> 6, b = tid & 63;
  int g = w & 3, kq = w >> 2;          // gate 0..3, K-quarter 0..3
  int grow = g*EE + e;
  const float* wh = W_hh + (size_t)grow*EE + kq*64;
  const float* wi = W_ih + (size_t)grow*EE + kq*64;
  const float* hT = hT_cur + kq*64*BB;
  const float* xv = xT_st + kq*64*BB;
  float acc = (kq == 0) ? (b_ih[grow] + b_hh[grow]) : 0.0f;
  #pragma unroll 4
  for (int k4 = 0; k4 < 16; ++k4){
    vf4 wh4 = *(const vf4*)(wh + k4*4);
    vf4 wi4 = *(const vf4*)(wi + k4*4);
    int k = k4*4;
    acc += hT[(k+0)*BB+b]*wh4.x + hT[(k+1)*BB+b]*wh4.y
         + hT[(k+2)*BB+b]*wh4.z + hT[(k+3)*BB+b]*wh4.w;
    acc += xv[(k+0)*BB+b]*wi4.x + xv[(k+1)*BB+b]*wi4.y
         + xv[(k+2)*BB+b]*wi4.z + xv[(k+3)*BB+b]*wi4.w;
  }
  __shared__ float sm[16][BB];
  sm[w][b] = acc;
  __syncthreads();
  if (tid < BB){
    float iv = sm[0][tid]+sm[4][tid]+sm[8][tid] +sm[12][tid];
    float fv = sm[1][tid]+sm[5][tid]+sm[9][tid] +sm[13][tid];
    float gv = sm[2][tid]+sm[6][tid]+sm[10][tid]+sm[14][tid];
    float ov = sm[3][tid]+sm[7][tid]+sm[11][tid]+sm[15][tid];
    float cprev = cT[e*BB + tid];
    float cn = sigm(fv)*cprev + sigm(iv)*tanhf(gv);
    float hn = sigm(ov)*tanhf(cn);
    cT[e*BB + tid] = cn;
    hT_next[e*BB + tid] = hn;
    hs_st[(size_t)tid*EE + e] = hn;
  }
}

// ---- 2) single-pass register-held attend: scores+softmax+mix (+encb) --------
// grid: 64 b x 32 chunks of 64 rows; 256 threads (4 waves)
// thread (wv, rs=lane>>4, cg=lane&15) holds rows {wv*16+i*4+rs}, cols [cg*16,+16)
__global__ __launch_bounds__(256) void k_attend(
  const float* __restrict__ enc, const float* __restrict__ hs,
  float* __restrict__ mixc, float* __restrict__ stats,
  unsigned short* __restrict__ encb)
{
  int bid = blockIdx.x; int b = bid >> 5, ch = bid & 31;
  int tid = threadIdx.x, lane = tid & 63, wv = tid >> 6;
  int rs = lane >> 4, cg = lane & 15;
  __shared__ float qsm[3][EE];      // 3 KB
  __shared__ float sc[3][64];
  __shared__ vf4 mpart[4][3][64];   // 12 KB

  const float* chunk = enc + ((size_t)b*SS + ch*64)*EE;

  // issue ALL enc loads upfront (only read of enc in this kernel)
  vf4 dat[4][4];
  #pragma unroll
  for (int i=0;i<4;++i){
    const vf4* rp = (const vf4*)(chunk + (size_t)(wv*16 + i*4 + rs)*EE + cg*16);
    #pragma unroll
    for (int v=0;v<4;++v) dat[i][v] = rp[v];
  }
  for (int i = tid; i < 3*EE; i += 256)
    qsm[i>>8][i&255] = hs[((size_t)(i>>8)*BB + b)*EE + (i&255)];
  __syncthreads();

  // scores from registers
  {
    vf4 q0[4], q1[4], q2[4];
    #pragma unroll
    for (int v=0;v<4;++v){
      q0[v] = *(const vf4*)(qsm[0] + cg*16 + v*4);
      q1[v] = *(const vf4*)(qsm[1] + cg*16 + v*4);
      q2[v] = *(const vf4*)(qsm[2] + cg*16 + v*4);
    }
    #pragma unroll
    for (int i=0;i<4;++i){
      float a0=0.f, a1=0.f, a2=0.f;
      #pragma unroll
      for (int v=0;v<4;++v){
        a0 += dot4(dat[i][v], q0[v]);
        a1 += dot4(dat[i][v], q1[v]);
        a2 += dot4(dat[i][v], q2[v]);
      }
      #pragma unroll
      for (int d=1; d<16; d<<=1){
        a0 += __shfl_xor(a0,d); a1 += __shfl_xor(a1,d); a2 += __shfl_xor(a2,d);
      }
      if (cg == 0){
        int r = wv*16 + i*4 + rs;
        sc[0][r]=a0; sc[1][r]=a1; sc[2][r]=a2;
      }
    }
  }
  __syncthreads();

  // softmax: every wave redundantly, lane owns row=lane
  float e0, e1, e2;
  {
    float s0 = sc[0][lane], s1 = sc[1][lane], s2 = sc[2][lane];
    float m0=s0, m1=s1, m2=s2;
    #pragma unroll
    for (int d=1; d<64; d<<=1){
      m0 = fmaxf(m0, __shfl_xor(m0,d));
      m1 = fmaxf(m1, __shfl_xor(m1,d));
      m2 = fmaxf(m2, __shfl_xor(m2,d));
    }
    e0 = __expf(s0-m0); e1 = __expf(s1-m1); e2 = __expf(s2-m2);
    float l0=e0, l1=e1, l2=e2;
    #pragma unroll
    for (int d=1; d<64; d<<=1){
      l0 += __shfl_xor(l0,d); l1 += __shfl_xor(l1,d); l2 += __shfl_xor(l2,d);
    }
    if (tid == 0){
      int o0 = ((0*BB+b)*NCH + ch)*2; stats[o0]=m0; stats[o0+1]=l0;
      int o1 = ((1*BB+b)*NCH + ch)*2; stats[o1]=m1; stats[o1+1]=l1;
      int o2 = ((2*BB+b)*NCH + ch)*2; stats[o2]=m2; stats[o2+1]=l2;
    }
  }

  // mix + encb write, all from held registers (no enc re-read)
  vf4 A0[4], A1[4], A2[4];
  #pragma unroll
  for (int v=0;v<4;++v){ A0[v]=(vf4)0.0f; A1[v]=(vf4)0.0f; A2[v]=(vf4)0.0f; }
  #pragma unroll
  for (int i=0;i<4;++i){
    int r = wv*16 + i*4 + rs;
    int gs = ch*64 + r;
    float w0 = __shfl(e0, r), w1 = __shfl(e1, r), w2 = __shfl(e2, r);
    if (encb){
      int key = ((gs + 1) & 7) << 4;
      char* base = (char*)encb + ((size_t)b*SS + gs)*512;
      u32x4 lo4, hi4;
      lo4.x = f2bf2(dat[i][0].x, dat[i][0].y); lo4.y = f2bf2(dat[i][0].z, dat[i][0].w);
      lo4.z = f2bf2(dat[i][1].x, dat[i][1].y); lo4.w = f2bf2(dat[i][1].z, dat[i][1].w);
      hi4.x = f2bf2(dat[i][2].x, dat[i][2].y); hi4.y = f2bf2(dat[i][2].z, dat[i][2].w);
      hi4.z = f2bf2(dat[i][3].x, dat[i][3].y); hi4.w = f2bf2(dat[i][3].z, dat[i][3].w);
      *(u32x4*)(base + ((cg*32     ) ^ key)) = lo4;
      *(u32x4*)(base + ((cg*32 + 16) ^ key)) = hi4;
    }
    #pragma unroll
    for (int v=0;v<4;++v){
      A0[v] += dat[i][v]*w0; A1[v] += dat[i][v]*w1; A2[v] += dat[i][v]*w2;
    }
  }
  // reduce partials across rs (lanes ^16, ^32)
  #pragma unroll
  for (int v=0;v<4;++v){
    #pragma unroll
    for (int d=16; d<64; d<<=1){
      A0[v].x += __shfl_xor(A0[v].x,d); A0[v].y += __shfl_xor(A0[v].y,d);
      A0[v].z += __shfl_xor(A0[v].z,d); A0[v].w += __shfl_xor(A0[v].w,d);
      A1[v].x += __shfl_xor(A1[v].x,d); A1[v].y += __shfl_xor(A1[v].y,d);
      A1[v].z += __shfl_xor(A1[v].z,d); A1[v].w += __shfl_xor(A1[v].w,d);
      A2[v].x += __shfl_xor(A2[v].x,d); A2[v].y += __shfl_xor(A2[v].y,d);
      A2[v].z += __shfl_xor(A2[v].z,d); A2[v].w += __shfl_xor(A2[v].w,d);
    }
  }
  if (rs == 0){
    #pragma unroll
    for (int v=0;v<4;++v){
      mpart[wv][0][cg*4+v] = A0[v];
      mpart[wv][1][cg*4+v] = A1[v];
      mpart[wv][2][cg*4+v] = A2[v];
    }
  }
  __syncthreads();
  if (tid < 192){
    int q = tid >> 6, e4 = tid & 63;
    vf4 sum = mpart[0][q][e4] + mpart[1][q][e4] + mpart[2][q][e4] + mpart[3][q][e4];
    *(vf4*)(mixc + ((size_t)(q*BB+b)*NCH + ch)*EE + e4*4) = sum;
  }
}

// ---------------- 4) combine chunk mixes; out_t; t1 logits; V vectors --------
__global__ __launch_bounds__(256) void k_post(
  const float* __restrict__ mixc, const float* __restrict__ hs,
  const float* __restrict__ stats,
  const float* __restrict__ W_attn, const float* __restrict__ b_attn,
  const float* __restrict__ W_rel, const float* __restrict__ b_rel,
  const unsigned short* __restrict__ WT, const float* __restrict__ b_conv,
  float* __restrict__ out, float* __restrict__ vv)
{
  int b = blockIdx.x, t = threadIdx.x;
  __shared__ float comb[3][2*EE];
  __shared__ float o1[EE], o2s[EE], o3s[EE];
  #pragma unroll
  for (int q=0;q<3;q++){
    float M = -1e30f;
    for (int c=0;c<NCH;c++) M = fmaxf(M, stats[((q*BB+b)*NCH + c)*2]);
    float L = 0.f, macc = 0.f;
    for (int c=0;c<NCH;c++){
      int o = ((q*BB+b)*NCH + c)*2;
      float e = __expf(stats[o]-M);
      L += stats[o+1]*e;
      macc += mixc[((size_t)(q*BB+b)*NCH + c)*EE + t] * e;
    }
    comb[q][t] = macc / L;
    comb[q][EE+t] = hs[((size_t)q*BB + b)*EE + t];
  }
  __syncthreads();
  float a0 = b_attn[t], a1 = a0, a2 = a0;
  const vf4* wr = (const vf4*)(W_attn + (size_t)t*2*EE);
  const vf4* c0v = (const vf4*)comb[0];
  const vf4* c1v = (const vf4*)comb[1];
  const vf4* c2v = (const vf4*)comb[2];
  #pragma unroll 4
  for (int k=0;k<2*EE/4;++k){
    vf4 w = wr[k];
    a0 += dot4(w, c0v[k]); a1 += dot4(w, c1v[k]); a2 += dot4(w, c2v[k]);
  }
  o1[t]=tanhf(a0); o2s[t]=tanhf(a1); o3s[t]=tanhf(a2);
  __syncthreads();
  if (t < RN){
    float acc = b_rel[t];
    const vf4* wrel = (const vf4*)(W_rel + (size_t)t*EE);
    const vf4* ov = (const vf4*)o1;
    for (int k=0;k<EE/4;++k) acc += dot4(wrel[k], ov[k]);
    out[(size_t)b*OSTR + t] = acc;
  }
  // V_k[o] = sum_i o[i]*WT[(i*3+k)][o]  (coalesced bf16 rows)
  float va0=0,va1=0,va2=0, vb0=0,vb1=0,vb2=0;
  for (int i=0;i<EE;++i){
    float x2 = o2s[i], x3 = o3s[i];
    const unsigned short* wt = WT + (size_t)i*3*EE + t;
    float w0 = __uint_as_float(((unsigned int)wt[0]) << 16);
    float w1 = __uint_as_float(((unsigned int)wt[EE]) << 16);
    float w2 = __uint_as_float(((unsigned int)wt[2*EE]) << 16);
    va0 += x2*w0; va1 += x2*w1; va2 += x2*w2;
    vb0 += x3*w0; vb1 += x3*w1; vb2 += x3*w2;
  }
  float bc = b_conv[t];
  vv[((0*3+0)*BB + b)*EE + t] = va0+va1+va2+bc;  // interior
  vv[((0*3+1)*BB + b)*EE + t] = va1+va2+bc;      // s==0 (tap0 clipped)
  vv[((0*3+2)*BB + b)*EE + t] = va0+va1+bc;      // s==S-1 (tap2 clipped)
  vv[((1*3+0)*BB + b)*EE + t] = vb0+vb1+vb2+bc;
  vv[((1*3+1)*BB + b)*EE + t] = vb1+vb2+bc;
  vv[((1*3+2)*BB + b)*EE + t] = vb0+vb1+bc;
}

// ---------------- 6) conv GEMM: C[o][s] = W·enc^T, MFMA relu-dot epilogue ----
__global__ __launch_bounds__(256, 3) void k_conv(
  const float* __restrict__ enc, const unsigned short* __restrict__ encb,
  const unsigned short* __restrict__ Bp,
  const float* __restrict__ vv,
  const float* __restrict__ W_e1, const float* __restrict__ b_e1,
  const float* __restrict__ W_e2, const float* __restrict__ b_e2,
  float* __restrict__ out)
{
  int stile = blockIdx.x, b = blockIdx.y;
  int s0 = stile*64;
  int tid = threadIdx.x, lane = tid & 63, w = tid >> 6;
  int lo = lane & 15, hi = lane >> 4;
  __shared__ __align__(16) unsigned short Ab[66*256];
  __shared__ float part2[4][64][4];

  if (encb){
    const char* ebase = (const char*)encb + (size_t)b*SS*512;
    for (int base = 0; base < 66*32; base += 256){
      int idx = base + tid;
      if (idx < 66*32){
        int r = idx >> 5, c = idx & 31;
        int srow = s0 - 1 + r;
        srow = srow < 0 ? 0 : (srow > SS-1 ? SS-1 : srow);
        gload_lds16(ebase + (size_t)srow*512 + c*16, (char*)Ab + idx*16);
      }
    }
    __syncthreads();
    if (stile == 0 || stile == 31){
      if (stile == 0  && tid < 32) *(vf4*)((char*)Ab + tid*16) = (vf4)0.0f;
      if (stile == 31 && tid < 32) *(vf4*)((char*)Ab + 65*512 + tid*16) = (vf4)0.0f;
      __syncthreads();
    }
  } else {
    const float* eb = enc + (size_t)b*SS*EE;
    for (int idx = tid; idx < 66*64; idx += 256){
      int r = idx >> 6, c4 = idx & 63;
      int s = s0 - 1 + r;
      vf4 v = (vf4)0.0f;
      if (s >= 0 && s < SS) v = *(const vf4*)(eb + (size_t)s*EE + c4*4);
      u32x2 pk; pk.x = f2bf2(v.x, v.y); pk.y = f2bf2(v.z, v.w);
      int byte = (r*512 + c4*8) ^ ((r & 7) << 4);
      *(u32x2*)((char*)Ab + byte) = pk;
    }
    __syncthreads();
  }

  vf4 acc[4][4];   // [oi][si], row=o col=s
  #pragma unroll
  for (int oi=0;oi<4;++oi){
    #pragma unroll
    for (int si=0;si<4;++si) acc[oi][si] = (vf4)0.0f;
  }
  const s8v* Bp8 = (const s8v*)Bp;
  s8v bf[4], bfn[4];
  #pragma unroll
  for (int oi=0;oi<4;++oi) bf[oi] = Bp8[((0*16 + (w*4+oi)) << 6) + lane];

  for (int kc=0; kc<24; ++kc){
    int ktap = kc >> 3;
    int colb = ((kc & 7) << 6) + (hi << 4);
    s8v af[4];
    #pragma unroll
    for (int si=0;si<4;++si){
      int row = si*16 + lo + ktap;
      int byte = row*512 + (colb ^ ((row & 7) << 4));
      af[si] = *(const s8v*)((const char*)Ab + byte);
    }
    if (kc < 23){
      #pragma unroll
      for (int oi=0;oi<4;++oi) bfn[oi] = Bp8[(((kc+1)*16 + (w*4+oi)) << 6) + lane];
    }
    #pragma unroll
    for (int oi=0;oi<4;++oi){
      #pragma unroll
      for (int si=0;si<4;++si)
        acc[oi][si] = __builtin_amdgcn_mfma_f32_16x16x32_bf16(bf[oi], af[si], acc[oi][si], 0, 0, 0);
    }
    #pragma unroll
    for (int oi=0;oi<4;++oi) bf[oi] = bfn[oi];
  }

  bool firstTile = (s0 == 0), lastTile = (s0 + 64 == SS);
  vf4 vaI[4], vbI[4]; s4v aw[4];
  #pragma unroll
  for (int oi=0;oi<4;++oi){
    int o4 = w*64 + oi*16 + hi*4;
    vaI[oi] = *(const vf4*)(vv + ((0*3+0)*BB + b)*EE + o4);
    vbI[oi] = *(const vf4*)(vv + ((1*3+0)*BB + b)*EE + o4);
    vf4 w1 = *(const vf4*)(W_e1 + o4);
    vf4 w2 = *(const vf4*)(W_e2 + o4);
    float e0 = (lo==0) ? w1.x : ((lo==1) ? w2.x : 0.0f);
    float e1 = (lo==0) ? w1.y : ((lo==1) ? w2.y : 0.0f);
    float e2 = (lo==0) ? w1.z : ((lo==1) ? w2.z : 0.0f);
    float e3 = (lo==0) ? w1.w : ((lo==1) ? w2.w : 0.0f);
    u32x2 t; t.x = f2bf2(e0, e1); t.y = f2bf2(e2, e3);
    aw[oi] = __builtin_bit_cast(s4v, t);
  }
  #pragma unroll
  for (int si=0; si<4; ++si){
    vf4 Da = (vf4)0.0f, Db = (vf4)0.0f;
    #pragma unroll
    for (int oi=0; oi<4; ++oi){
      int o4 = w*64 + oi*16 + hi*4;
      vf4 c = acc[oi][si];
      vf4 va = vaI[oi], vb = vbI[oi];
      if (firstTile && si==0 && lo==0){
        va = *(const vf4*)(vv + ((0*3+1)*BB + b)*EE + o4);
        vb = *(const vf4*)(vv + ((1*3+1)*BB + b)*EE + o4);
      }
      if (lastTile && si==3 && lo==15){
        va = *(const vf4*)(vv + ((0*3+2)*BB + b)*EE + o4);
        vb = *(const vf4*)(vv + ((1*3+2)*BB + b)*EE + o4);
      }
      float a0 = fmaxf(c.x+va.x,0.f), a1 = fmaxf(c.y+va.y,0.f);
      float a2 = fmaxf(c.z+va.z,0.f), a3 = fmaxf(c.w+va.w,0.f);
      float b0 = fmaxf(c.x+vb.x,0.f), b1 = fmaxf(c.y+vb.y,0.f);
      float b2 = fmaxf(c.z+vb.z,0.f), b3 = fmaxf(c.w+vb.w,0.f);
      u32x2 ta; ta.x = f2bf2(a0,a1); ta.y = f2bf2(a2,a3);
      u32x2 tb; tb.x = f2bf2(b0,b1); tb.y = f2bf2(b2,b3);
      Da = mfma16(aw[oi], __builtin_bit_cast(s4v, ta), Da);
      Db = mfma16(aw[oi], __builtin_bit_cast(s4v, tb), Db);
    }
    if (hi == 0){
      vf4 pk; pk.x = Da.x; pk.y = Da.y; pk.z = Db.x; pk.w = Db.y;
      *(vf4*)&part2[w][si*16+lo][0] = pk;
    }
  }
  __syncthreads();
  {
    int s = tid >> 2, c = tid & 3;
    float r = part2[0][s][c] + part2[1][s][c] + part2[2][s][c] + part2[3][s][c];
    r += (c & 1) ? b_e2[0] : b_e1[0];
    out[(size_t)b*OSTR + RN + c*SS + (s0 + s)] = r;
  }
}

extern "C" void kernel_launch(void* const* d_in, const int* in_sizes, int n_in,
                              void* d_out, int out_size, void* d_ws, size_t ws_size,
                              hipStream_t stream)
{
  const float* enc   = (const float*)d_in[0];
  const float* h0    = (const float*)d_in[1];
  const float* c0    = (const float*)d_in[2];
  const int*   r_in  = (const int*)d_in[3];
  const int*   k1    = (const int*)d_in[4];
  const int*   k2    = (const int*)d_in[5];
  const float* W_ih  = (const float*)d_in[6];
  const float* W_hh  = (const float*)d_in[7];
  const float* b_ih  = (const float*)d_in[8];
  const float* b_hh  = (const float*)d_in[9];
  const float* W_attn= (const float*)d_in[10];
  const float* b_attn= (const float*)d_in[11];
  const float* W_conv= (const float*)d_in[12];
  const float* b_conv= (const float*)d_in[13];
  const float* sos   = (const float*)d_in[14];
  const float* rel   = (const float*)d_in[15];
  const float* W_rel = (const float*)d_in[16];
  const float* b_rel = (const float*)d_in[17];
  const float* W_e1  = (const float*)d_in[18];
  const float* b_e1  = (const float*)d_in[19];
  const float* W_e2  = (const float*)d_in[20];
  const float* b_e2  = (const float*)d_in[21];
  float* out = (float*)d_out;
  char* ws = (char*)d_ws;

  float* hs    = (float*)(ws);                  // 3*64*256 f32        (196608 B)
  float* vv    = (float*)(ws + 196608);         // 2*3*64*256 f32      (393216 B)
  float* stats = (float*)(ws + 589824);         // 3*64*32*2 f32       ( 49152 B)
  float* mixc  = (float*)(ws + 638976);         // 3*64*32*256 f32     (6291456 B)
  unsigned short* Bp = (unsigned short*)(ws + 6930432);  // (393216 B)
  float* xT    = (float*)(ws + 7323648);        // 3*256*64 f32        (196608 B)
  float* hTa   = (float*)(ws + 7520256);        // 256*64 f32          ( 65536 B)
  float* hTb   = (float*)(ws + 7585792);        // 256*64 f32          ( 65536 B)
  float* cT    = (float*)(ws + 7651328);        // 256*64 f32          ( 65536 B)
  unsigned short* WT = (unsigned short*)(ws + 7716864);  // 768*256 bf16 (393216 B)
  size_t encb_off = 8110080;
  size_t need = encb_off + (size_t)BB*SS*EE*2;           // + 67108864 = ~75.2 MB
  unsigned short* encb = (ws_size >= need) ? (unsigned short*)(ws + encb_off) : nullptr;

  hipLaunchKernelGGL(k_prep,  dim3(608), dim3(256), 0, stream,
                     enc,h0,c0,r_in,k1,k2,sos,rel,W_conv, xT,hTa,cT, WT,Bp);
  hipLaunchKernelGGL(k_step,  dim3(256), dim3(1024), 0, stream,
                     hTa, xT + 0*EE*BB, W_ih,W_hh,b_ih,b_hh, cT, hTb, hs + 0*BB*EE);
  hipLaunchKernelGGL(k_step,  dim3(256), dim3(1024), 0, stream,
                     hTb, xT + 1*EE*BB, W_ih,W_hh,b_ih,b_hh, cT, hTa, hs + 1*BB*EE);
  hipLaunchKernelGGL(k_step,  dim3(256), dim3(1024), 0, stream,
                     hTa, xT + 2*EE*BB, W_ih,W_hh,b_ih,b_hh, cT, hTb, hs + 2*BB*EE);
  hipLaunchKernelGGL(k_attend,dim3(2048), dim3(256), 0, stream, enc, hs, mixc, stats, encb);
  hipLaunchKernelGGL(k_post,  dim3(64),  dim3(256), 0, stream,
                     mixc, hs, stats, W_attn,b_attn, W_rel,b_rel, WT, b_conv, out, vv);
  hipLaunchKernelGGL(k_conv,  dim3(32,64), dim3(256), 0, stream,
                     enc, encb, Bp, vv, W_e1,b_e1, W_e2,b_e2, out);
}